// Round 1
// 126.070 us; speedup vs baseline: 1.5958x; 1.5958x over previous
//
#include <hip/hip_runtime.h>
#include <math.h>

#define CH 64
#define TT 1000
#define NTRI 2080

typedef __attribute__((ext_vector_type(8))) short bf16x8;
typedef __attribute__((ext_vector_type(4))) float f32x4;
typedef __attribute__((ext_vector_type(4))) unsigned short u16x4;

__device__ __forceinline__ unsigned short f2bf(float f) {
    unsigned u = __builtin_bit_cast(unsigned, f);
    u += 0x7FFFu + ((u >> 16) & 1u);          // round-to-nearest-even
    return (unsigned short)(u >> 16);
}
__device__ __forceinline__ float bf2f(unsigned short h) {
    unsigned u = ((unsigned)h) << 16;
    return __builtin_bit_cast(float, u);
}
// element (r,c) of a [64][64] bf16 array, 16B-chunk XOR swizzle (2-way max)
__device__ __forceinline__ int sidx(int r, int c) {
    return (r << 6) + ((((c >> 3) ^ (r & 7)) << 3) | (c & 7));
}
// fragment base: 8 consecutive bf16 of row r, chunk ch (ch = k/8)
__device__ __forceinline__ int fidx(int r, int ch) {
    return (r << 6) + ((ch ^ (r & 7)) << 3);
}

// 64x64 * 64x64 symmetric-operand matmul band: wave w computes rows [16w,16w+16).
// A, B given as bf16 hi/lo pairs in swizzled layout. acc[c] += A*B for col-band c.
// Split-2 bf16: (Ah+Al)(Bh+Bl) ~ AhBh + AhBl + AlBh.
__device__ __forceinline__ void mm64(const unsigned short* Ah, const unsigned short* Al,
                                     const unsigned short* Bh, const unsigned short* Bl,
                                     int w, int l, f32x4* acc) {
    const int lc = l & 15, hq = l >> 4;
    const int ar = (w << 4) + lc;
    bf16x8 ah[2], al[2];
    #pragma unroll
    for (int ks = 0; ks < 2; ++ks) {
        ah[ks] = *(const bf16x8*)&Ah[fidx(ar, ks * 4 + hq)];
        al[ks] = *(const bf16x8*)&Al[fidx(ar, ks * 4 + hq)];
    }
    #pragma unroll
    for (int c = 0; c < 4; ++c) {
        const int br = (c << 4) + lc;
        #pragma unroll
        for (int ks = 0; ks < 2; ++ks) {
            bf16x8 bh = *(const bf16x8*)&Bh[fidx(br, ks * 4 + hq)];
            bf16x8 bl = *(const bf16x8*)&Bl[fidx(br, ks * 4 + hq)];
            acc[c] = __builtin_amdgcn_mfma_f32_16x16x32_bf16(ah[ks], bh, acc[c], 0, 0, 0);
            acc[c] = __builtin_amdgcn_mfma_f32_16x16x32_bf16(ah[ks], bl, acc[c], 0, 0, 0);
            acc[c] = __builtin_amdgcn_mfma_f32_16x16x32_bf16(al[ks], bh, acc[c], 0, 0, 0);
        }
    }
}

__global__ __launch_bounds__(256, 4) void spd_logm_kernel(const float* __restrict__ x,
                                                          float* __restrict__ out) {
    const int m   = blockIdx.x;
    const int tid = threadIdx.x;
    const float* xp = x + (size_t)m * (CH * TT);

    // 32 KB total, 4 regions of 8 KB. Roles:
    //   phase 1: B0h/B0l = X tile (even t), B1h/B1l = X tile (odd t)  [double buffer]
    //   phase 2a: B0 = E, B1 = E^2 (P2)
    //   phase 2b (after E^3): B0 = E^3 (P3), B1 = R
    __shared__ __align__(16) unsigned short smem[16384];
    unsigned short* const B0h = smem;
    unsigned short* const B0l = smem + 4096;
    unsigned short* const B1h = smem + 8192;
    unsigned short* const B1l = smem + 12288;
    __shared__ float sRed[CH];
    __shared__ float sTr[4];

    const int w  = tid >> 6;   // wave id -> row band [16w, 16w+16)
    const int l  = tid & 63;
    const int lc = l & 15;     // C-layout col within tile
    const int hq = l >> 4;     // C-layout row quad

    const f32x4 z4 = {0.f, 0.f, 0.f, 0.f};

    // ---------------- Phase 1: G = X * X^T via MFMA (pipelined) ----------------
    f32x4 acc[4] = {z4, z4, z4, z4};

    const int srow = tid >> 2, sq = tid & 3;  // staging: thread -> row, col-slice
    const float* xrow = xp + srow * TT;
    float psum = 0.f;

    // prologue: prefetch tile 0 (cols 0..63, all < TT)
    float4 pf0 = *(const float4*)&xrow[sq * 4];
    float4 pf1 = *(const float4*)&xrow[sq * 4 + 16];
    float4 pf2 = *(const float4*)&xrow[sq * 4 + 32];
    float4 pf3 = *(const float4*)&xrow[sq * 4 + 48];

    for (int t = 0; t < 16; ++t) {
        unsigned short* Xh = (t & 1) ? B1h : B0h;
        unsigned short* Xl = (t & 1) ? B1l : B0l;

        // convert + store the prefetched tile
        float4 vv[4] = {pf0, pf1, pf2, pf3};
        #pragma unroll
        for (int q4 = 0; q4 < 4; ++q4) {
            float4 v = vv[q4];
            psum += v.x + v.y + v.z + v.w;
            const int kl = sq * 4 + q4 * 16;
            u16x4 hv, lv;
            hv[0] = f2bf(v.x); lv[0] = f2bf(v.x - bf2f(hv[0]));
            hv[1] = f2bf(v.y); lv[1] = f2bf(v.y - bf2f(hv[1]));
            hv[2] = f2bf(v.z); lv[2] = f2bf(v.z - bf2f(hv[2]));
            hv[3] = f2bf(v.w); lv[3] = f2bf(v.w - bf2f(hv[3]));
            const int idx = (srow << 6) + ((((kl >> 3) ^ (srow & 7)) << 3) | (kl & 7));
            *(u16x4*)&Xh[idx] = hv;
            *(u16x4*)&Xl[idx] = lv;
        }

        // issue next tile's loads; they stay in flight across the barrier
        if (t < 15) {
            const int kb = ((t + 1) << 6) + sq * 4;
            pf0 = (kb      < TT) ? *(const float4*)&xrow[kb]      : make_float4(0.f, 0.f, 0.f, 0.f);
            pf1 = (kb + 16 < TT) ? *(const float4*)&xrow[kb + 16] : make_float4(0.f, 0.f, 0.f, 0.f);
            pf2 = (kb + 32 < TT) ? *(const float4*)&xrow[kb + 32] : make_float4(0.f, 0.f, 0.f, 0.f);
            pf3 = (kb + 48 < TT) ? *(const float4*)&xrow[kb + 48] : make_float4(0.f, 0.f, 0.f, 0.f);
        }

        // drain only LDS writes (NOT the prefetch vmcnt), then raw barrier.
        // Safe: stores(t) target buf[t&1], last read by mm64(t-2); every wave's
        // mm64(t-2) ds_reads drained at its own lgkmcnt(0) before barrier(t-1).
        asm volatile("s_waitcnt lgkmcnt(0)" ::: "memory");
        __builtin_amdgcn_s_barrier();
        __builtin_amdgcn_sched_barrier(0);

        mm64(Xh, Xl, Xh, Xl, w, l, acc);
    }

    // row sums (4 threads per row are adjacent lanes)
    psum += __shfl_xor(psum, 1, 64);
    psum += __shfl_xor(psum, 2, 64);
    if (sq == 0) sRed[srow] = psum;
    __syncthreads();   // also drains all of phase 1 (mm64(15) reads included)

    // ---------------- cov, trace, E ----------------
    const float invT = 1.f / (float)TT, invTm1 = 1.f / (float)(TT - 1);
    float Srow[4], Scol[4];
    #pragma unroll
    for (int r = 0; r < 4; ++r) Srow[r] = sRed[(w << 4) + hq * 4 + r];
    #pragma unroll
    for (int c = 0; c < 4; ++c) Scol[c] = sRed[(c << 4) + lc];

    float covv[4][4];
    float trp = 0.f;
    #pragma unroll
    for (int c = 0; c < 4; ++c)
        #pragma unroll
        for (int r = 0; r < 4; ++r) {
            covv[c][r] = (acc[c][r] - Srow[r] * Scol[c] * invT) * invTm1;
            if (c == w && lc == hq * 4 + r) trp += covv[c][r];
        }
    trp += __shfl_xor(trp, 1, 64);  trp += __shfl_xor(trp, 2, 64);
    trp += __shfl_xor(trp, 4, 64);  trp += __shfl_xor(trp, 8, 64);
    trp += __shfl_xor(trp, 16, 64); trp += __shfl_xor(trp, 32, 64);
    if (l == 0) sTr[w] = trp;
    __syncthreads();
    const float s    = (sTr[0] + sTr[1] + sTr[2] + sTr[3]) * (1.f / 64.f);
    const float invs = 1.f / s;
    const float logs = logf(s);

    // E = cov/s - I  -> B0 (overwrites X buf 0; all phase-1 reads drained above)
    float Ev[4][4], e2v[4][4];
    #pragma unroll
    for (int c = 0; c < 4; ++c)
        #pragma unroll
        for (int r = 0; r < 4; ++r) {
            const int row = (w << 4) + hq * 4 + r, col = (c << 4) + lc;
            const float e = covv[c][r] * invs - ((row == col) ? 1.f : 0.f);
            Ev[c][r] = e;
            const unsigned short h = f2bf(e);
            B0h[sidx(row, col)] = h;
            B0l[sidx(row, col)] = f2bf(e - bf2f(h));
        }
    __syncthreads();

    // ---------------- Phase 2: Paterson-Stockmeyer deg-15 ----------------
    // E^2 -> B1
    f32x4 a2[4] = {z4, z4, z4, z4};
    mm64(B0h, B0l, B0h, B0l, w, l, a2);
    #pragma unroll
    for (int c = 0; c < 4; ++c)
        #pragma unroll
        for (int r = 0; r < 4; ++r) {
            const int row = (w << 4) + hq * 4 + r, col = (c << 4) + lc;
            const float v = a2[c][r];
            e2v[c][r] = v;
            const unsigned short h = f2bf(v);
            B1h[sidx(row, col)] = h;
            B1l[sidx(row, col)] = f2bf(v - bf2f(h));
        }
    __syncthreads();

    // E^3 = E * E^2
    f32x4 a3[4] = {z4, z4, z4, z4};
    mm64(B0h, B0l, B1h, B1l, w, l, a3);
    __syncthreads();   // all reads of E (B0) and E^2 (B1) complete before overwrite

    // P3 = E^3 -> B0 (over E); R init = c12 I + c13 E + c14 E^2 + c15 E^3 -> B1 (over E^2)
    #pragma unroll
    for (int c = 0; c < 4; ++c)
        #pragma unroll
        for (int r = 0; r < 4; ++r) {
            const int row = (w << 4) + hq * 4 + r, col = (c << 4) + lc;
            const float e3 = a3[c][r];
            unsigned short h = f2bf(e3);
            B0h[sidx(row, col)] = h;
            B0l[sidx(row, col)] = f2bf(e3 - bf2f(h));
            float rv = (1.f/15.f) * e3 + (-1.f/14.f) * e2v[c][r] + (1.f/13.f) * Ev[c][r]
                     + ((row == col) ? (-1.f/12.f) : 0.f);
            h = f2bf(rv);
            B1h[sidx(row, col)] = h;
            B1l[sidx(row, col)] = f2bf(rv - bf2f(h));
        }
    __syncthreads();

    // Horner: R = E^3*R + (c_{3j} I + c_{3j+1} E + c_{3j+2} E^2), j = 3,2,1
    const float CJ[3][3] = {
        { 1.f/9.f, -1.f/10.f,  1.f/11.f },   // j=3
        {-1.f/6.f,  1.f/7.f,  -1.f/8.f  },   // j=2
        { 1.f/3.f, -1.f/4.f,   1.f/5.f  },   // j=1
    };
    #pragma unroll
    for (int jj = 0; jj < 3; ++jj) {
        f32x4 ar[4] = {z4, z4, z4, z4};
        mm64(B0h, B0l, B1h, B1l, w, l, ar);
        __syncthreads();                      // all reads of old R complete
        const float c0 = CJ[jj][0], c1 = CJ[jj][1], c2 = CJ[jj][2];
        #pragma unroll
        for (int c = 0; c < 4; ++c)
            #pragma unroll
            for (int r = 0; r < 4; ++r) {
                const int row = (w << 4) + hq * 4 + r, col = (c << 4) + lc;
                float rv = ar[c][r] + c1 * Ev[c][r] + c2 * e2v[c][r]
                         + ((row == col) ? c0 : 0.f);
                const unsigned short h = f2bf(rv);
                B1h[sidx(row, col)] = h;
                B1l[sidx(row, col)] = f2bf(rv - bf2f(h));
            }
        __syncthreads();                      // new R visible
    }

    // final: p = E^3*R + 1*E - 0.5*E^2 ; output logm = p + log(s) I, triu only
    f32x4 aF[4] = {z4, z4, z4, z4};
    mm64(B0h, B0l, B1h, B1l, w, l, aF);
    const size_t ob = (size_t)m * NTRI;
    #pragma unroll
    for (int c = 0; c < 4; ++c)
        #pragma unroll
        for (int r = 0; r < 4; ++r) {
            const int row = (w << 4) + hq * 4 + r, col = (c << 4) + lc;
            if (row <= col) {
                float v = aF[c][r] + Ev[c][r] - 0.5f * e2v[c][r]
                        + ((row == col) ? logs : 0.f);
                out[ob + row * (2 * CH - row + 1) / 2 + (col - row)] = v;
            }
        }
}

extern "C" void kernel_launch(void* const* d_in, const int* in_sizes, int n_in,
                              void* d_out, int out_size, void* d_ws, size_t ws_size,
                              hipStream_t stream) {
    const float* x = (const float*)d_in[0];
    float* out = (float*)d_out;
    const int nm = in_sizes[0] / (CH * TT);   // B*F = 2048
    spd_logm_kernel<<<nm, 256, 0, stream>>>(x, out);
}